// Round 2
// baseline (319.963 us; speedup 1.0000x reference)
//
#include <hip/hip_runtime.h>

// ---------- problem dims ----------
constexpr int B_ = 16, C_ = 64, F_ = 40, T_ = 512;
constexpr int D_ = F_ * C_;              // 2560
constexpr float SCALE = 0.019764235376052372f;  // 1/sqrt(2560)

// ---------- types ----------
typedef __attribute__((ext_vector_type(8))) short s16x8;
typedef __attribute__((ext_vector_type(4))) short s16x4;
typedef __attribute__((ext_vector_type(4))) float f32x4;

static __device__ __forceinline__ short f2bf(float f) {
  union { float f; unsigned u; } v; v.f = f;
  unsigned r = v.u + 0x7fffu + ((v.u >> 16) & 1u);   // RNE, no NaN inputs
  return (short)(r >> 16);
}

static __device__ __forceinline__ f32x4 mfma16(s16x8 a, s16x8 b, f32x4 c) {
  return __builtin_amdgcn_mfma_f32_16x16x32_bf16(a, b, c, 0, 0, 0);
}

// =====================================================================
// Kernel 1: 1x1-conv projections.  Per block: one (b, f, 128-wide t tile).
// Y[o][t] = sum_c W[o][c] * x[b][c][f][t]   for W in {Wq, Wk, Wv}
// Q,K stored [b][t][d] bf16 (d = f*64+o);  V stored [b][d][t] bf16 via
// operand-swapped MFMA (D[m=t][n=o] -> 4 acc regs = 4 consecutive t).
// W fragments loaded straight from global (L2-hot), no W LDS.
// =====================================================================
__global__ __launch_bounds__(256) void proj_kernel(
    const float* __restrict__ x,
    const float* __restrict__ Wq, const float* __restrict__ Wk,
    const float* __restrict__ Wv,
    short* __restrict__ Q, short* __restrict__ K, short* __restrict__ V)
{
  constexpr int XS = 132;   // X lds row stride (shorts)
  __shared__ short Xl[64 * XS];   // [c][t] tile, 16.9 KB

  const int b = blockIdx.z, f = blockIdx.y, tt = blockIdx.x;  // tt: 0..3
  const int tid = threadIdx.x;

  // stage X tile [64 c][128 t] as bf16 (coalesced float4 loads)
  const float* xp = x + (((size_t)b * 64) * 40 + f) * 512 + tt * 128;
  #pragma unroll
  for (int it = 0; it < 8; ++it) {          // 64c x 32 float4-granules
    const int i = tid + it * 256;
    const int c = i >> 5, j = i & 31;
    const float4 v4 = *(const float4*)(xp + (size_t)c * (F_ * T_) + j * 4);
    s16x4 s4; s4[0] = f2bf(v4.x); s4[1] = f2bf(v4.y);
    s4[2] = f2bf(v4.z); s4[3] = f2bf(v4.w);
    *(s16x4*)&Xl[c * XS + j * 4] = s4;
  }
  __syncthreads();

  const int w = tid >> 6, lane = tid & 63;
  const int quad = lane >> 4, c16 = lane & 15;
  const int tl = w * 32;                    // wave's t-base within tile

  // X fragments, shared by all three projections.
  // frag[ni][ks][j] = X[c = ks*32+quad*8+j][t = tl+ni*16+c16]
  s16x8 bfrag[2][2];
  #pragma unroll
  for (int ni = 0; ni < 2; ++ni)
    #pragma unroll
    for (int ks = 0; ks < 2; ++ks) {
      const int t = tl + ni * 16 + c16;
      const int cb = ks * 32 + quad * 8;
      s16x8 tmp;
      #pragma unroll
      for (int j = 0; j < 8; ++j) tmp[j] = Xl[(cb + j) * XS + t];
      bfrag[ni][ks] = tmp;
    }

  #pragma unroll
  for (int p = 0; p < 3; ++p) {
    const float* Wp = (p == 0) ? Wq : (p == 1) ? Wk : Wv;
    // W fragment: rows o = mi*16+c16, cols c = ks*32+quad*8 .. +8 (fp32->bf16)
    s16x8 wfrag[4][2];
    #pragma unroll
    for (int mi = 0; mi < 4; ++mi)
      #pragma unroll
      for (int ks = 0; ks < 2; ++ks) {
        const float* wp = Wp + (mi * 16 + c16) * 64 + ks * 32 + quad * 8;
        const float4 w0 = *(const float4*)(wp);
        const float4 w1 = *(const float4*)(wp + 4);
        s16x8 wf;
        wf[0] = f2bf(w0.x); wf[1] = f2bf(w0.y); wf[2] = f2bf(w0.z); wf[3] = f2bf(w0.w);
        wf[4] = f2bf(w1.x); wf[5] = f2bf(w1.y); wf[6] = f2bf(w1.z); wf[7] = f2bf(w1.w);
        wfrag[mi][ks] = wf;
      }

    if (p < 2) {
      // D[m=o][n=t]
      f32x4 acc[4][2] = {};
      #pragma unroll
      for (int ks = 0; ks < 2; ++ks)
        #pragma unroll
        for (int mi = 0; mi < 4; ++mi)
          #pragma unroll
          for (int ni = 0; ni < 2; ++ni)
            acc[mi][ni] = mfma16(wfrag[mi][ks], bfrag[ni][ks], acc[mi][ni]);
      short* outp = (p == 0) ? Q : K;
      #pragma unroll
      for (int mi = 0; mi < 4; ++mi)
        #pragma unroll
        for (int ni = 0; ni < 2; ++ni) {
          const int t = tt * 128 + tl + ni * 16 + c16;
          const int o = mi * 16 + quad * 4;
          s16x4 s4;
          #pragma unroll
          for (int r = 0; r < 4; ++r) s4[r] = f2bf(acc[mi][ni][r]);
          *(s16x4*)&outp[((size_t)(b * 512 + t)) * D_ + f * 64 + o] = s4;
        }
    } else {
      // swapped: D[m=t][n=o] -> regs are 4 consecutive t
      f32x4 acc[2][4] = {};
      #pragma unroll
      for (int ks = 0; ks < 2; ++ks)
        #pragma unroll
        for (int ni = 0; ni < 2; ++ni)
          #pragma unroll
          for (int mi = 0; mi < 4; ++mi)
            acc[ni][mi] = mfma16(bfrag[ni][ks], wfrag[mi][ks], acc[ni][mi]);
      #pragma unroll
      for (int ni = 0; ni < 2; ++ni)
        #pragma unroll
        for (int mi = 0; mi < 4; ++mi) {
          const int t = tt * 128 + tl + ni * 16 + quad * 4;
          const int o = mi * 16 + c16;
          s16x4 s4;
          #pragma unroll
          for (int r = 0; r < 4; ++r) s4[r] = f2bf(acc[ni][mi][r]);
          *(s16x4*)&V[((size_t)(b * D_ + f * 64 + o)) * 512 + t] = s4;
        }
    }
  }
}

// =====================================================================
// Kernel 2: S = Q K^T / sqrt(d).  64x128 tile (512 blocks -> 2/CU),
// BK=32, NT layout, wave tile 32x64.
// =====================================================================
__global__ __launch_bounds__(256) void scores_kernel(
    const short* __restrict__ Q, const short* __restrict__ K,
    float* __restrict__ S)
{
  __shared__ short As[64 * 32];
  __shared__ short Bs[128 * 32];
  const int b = blockIdx.y;
  const int mt = blockIdx.x >> 2, nt = blockIdx.x & 3;
  const int m0 = mt * 64, n0 = nt * 128;
  const int tid = threadIdx.x;
  const int w = tid >> 6, lane = tid & 63, quad = lane >> 4, c16 = lane & 15;
  const int wm = (w >> 1) * 32, wn = (w & 1) * 64;
  const int r0 = tid >> 2, cc8 = (tid & 3) * 8;

  const short* qrow  = Q + ((size_t)(b * 512 + m0 + r0)) * D_ + cc8;
  const short* krow0 = K + ((size_t)(b * 512 + n0 + r0)) * D_ + cc8;
  const short* krow1 = krow0 + (size_t)64 * D_;

  f32x4 acc[2][4] = {};
  s16x8 a0 = *(const s16x8*)(qrow);
  s16x8 b0 = *(const s16x8*)(krow0);
  s16x8 b1 = *(const s16x8*)(krow1);

  constexpr int NK = D_ / 32;   // 80
  for (int kk = 0; kk < NK; ++kk) {
    __syncthreads();
    *(s16x8*)&As[r0 * 32 + cc8] = a0;
    *(s16x8*)&Bs[r0 * 32 + cc8] = b0;
    *(s16x8*)&Bs[(64 + r0) * 32 + cc8] = b1;
    __syncthreads();
    if (kk + 1 < NK) {                 // prefetch next tile (overlaps MFMA)
      const int off = (kk + 1) * 32;
      a0 = *(const s16x8*)(qrow + off);
      b0 = *(const s16x8*)(krow0 + off);
      b1 = *(const s16x8*)(krow1 + off);
    }
    s16x8 am[2], bm[4];
    #pragma unroll
    for (int mi = 0; mi < 2; ++mi)
      am[mi] = *(const s16x8*)&As[(wm + mi * 16 + c16) * 32 + quad * 8];
    #pragma unroll
    for (int ni = 0; ni < 4; ++ni)
      bm[ni] = *(const s16x8*)&Bs[(wn + ni * 16 + c16) * 32 + quad * 8];
    #pragma unroll
    for (int mi = 0; mi < 2; ++mi)
      #pragma unroll
      for (int ni = 0; ni < 4; ++ni)
        acc[mi][ni] = mfma16(am[mi], bm[ni], acc[mi][ni]);
  }

  float* sp = S + (size_t)b * 512 * 512;
  #pragma unroll
  for (int mi = 0; mi < 2; ++mi)
    #pragma unroll
    for (int ni = 0; ni < 4; ++ni) {
      const int kcol = n0 + wn + ni * 16 + c16;
      const int qrow_o = m0 + wm + mi * 16 + quad * 4;
      #pragma unroll
      for (int r = 0; r < 4; ++r)
        sp[(size_t)(qrow_o + r) * 512 + kcol] = acc[mi][ni][r] * SCALE;
    }
}

// =====================================================================
// Kernel 3: row softmax, S fp32 -> A bf16.  One WAVE per (b,q) row,
// 4 rows per block, no block-level barriers.
// =====================================================================
__global__ __launch_bounds__(256) void softmax_kernel(
    const float* __restrict__ S, short* __restrict__ A)
{
  const int b = blockIdx.y;
  const int tid = threadIdx.x, w = tid >> 6, lane = tid & 63;
  const int q = blockIdx.x * 4 + w;
  const float* row = S + ((size_t)b * 512 + q) * 512;

  const float4 v0 = *(const float4*)(row + lane * 4);
  const float4 v1 = *(const float4*)(row + 256 + lane * 4);
  float e[8] = {v0.x, v0.y, v0.z, v0.w, v1.x, v1.y, v1.z, v1.w};

  float m = e[0];
  #pragma unroll
  for (int i = 1; i < 8; ++i) m = fmaxf(m, e[i]);
  #pragma unroll
  for (int off = 1; off < 64; off <<= 1) m = fmaxf(m, __shfl_xor(m, off));

  float s = 0.f;
  #pragma unroll
  for (int i = 0; i < 8; ++i) { e[i] = __expf(e[i] - m); s += e[i]; }
  #pragma unroll
  for (int off = 1; off < 64; off <<= 1) s += __shfl_xor(s, off);

  const float inv = 1.0f / s;
  short* arow = A + ((size_t)b * 512 + q) * 512;
  s16x4 o0, o1;
  #pragma unroll
  for (int i = 0; i < 4; ++i) { o0[i] = f2bf(e[i] * inv); o1[i] = f2bf(e[i + 4] * inv); }
  *(s16x4*)&arow[lane * 4] = o0;
  *(s16x4*)&arow[256 + lane * 4] = o1;
}

// =====================================================================
// Kernel 4: out = A @ V.  A [b][q][k] bf16, V as Vt [b][d][t] bf16.
// Epilogue writes fp32 directly in [b][c][f][t] via float4 (regs = 4
// consecutive t).
// =====================================================================
__global__ __launch_bounds__(256) void pv_kernel(
    const short* __restrict__ A, const short* __restrict__ V,
    float* __restrict__ out)
{
  __shared__ short As[128 * 32];
  __shared__ short Bs[128 * 32];
  const int b = blockIdx.y;
  const int mt = blockIdx.x / 20, dt = blockIdx.x % 20;
  const int m0 = mt * 128, n0 = dt * 128;
  const int tid = threadIdx.x;
  const int w = tid >> 6, lane = tid & 63, quad = lane >> 4, c16 = lane & 15;
  const int wm = (w >> 1) * 64, wn = (w & 1) * 64;
  const int r0 = tid >> 2, cc8 = (tid & 3) * 8;

  const short* ab = A + (size_t)b * 512 * 512;
  const short* vb = V + (size_t)b * D_ * 512;
  const short* arow0 = ab + (size_t)(m0 + r0) * 512 + cc8;
  const short* arow1 = ab + (size_t)(m0 + 64 + r0) * 512 + cc8;
  const short* vrow0 = vb + (size_t)(n0 + r0) * 512 + cc8;
  const short* vrow1 = vb + (size_t)(n0 + 64 + r0) * 512 + cc8;

  f32x4 acc[4][4] = {};
  s16x8 a0 = *(const s16x8*)(arow0);
  s16x8 a1 = *(const s16x8*)(arow1);
  s16x8 b0 = *(const s16x8*)(vrow0);
  s16x8 b1 = *(const s16x8*)(vrow1);

  constexpr int NK = 512 / 32;   // 16
  for (int kk = 0; kk < NK; ++kk) {
    __syncthreads();
    *(s16x8*)&As[r0 * 32 + cc8] = a0;
    *(s16x8*)&As[(64 + r0) * 32 + cc8] = a1;
    *(s16x8*)&Bs[r0 * 32 + cc8] = b0;
    *(s16x8*)&Bs[(64 + r0) * 32 + cc8] = b1;
    __syncthreads();
    if (kk + 1 < NK) {
      const int off = (kk + 1) * 32;
      a0 = *(const s16x8*)(arow0 + off);
      a1 = *(const s16x8*)(arow1 + off);
      b0 = *(const s16x8*)(vrow0 + off);
      b1 = *(const s16x8*)(vrow1 + off);
    }
    s16x8 am[4], bm[4];
    #pragma unroll
    for (int mi = 0; mi < 4; ++mi)
      am[mi] = *(const s16x8*)&As[(wm + mi * 16 + c16) * 32 + quad * 8];
    #pragma unroll
    for (int ni = 0; ni < 4; ++ni)
      bm[ni] = *(const s16x8*)&Bs[(wn + ni * 16 + c16) * 32 + quad * 8];
    #pragma unroll
    for (int mi = 0; mi < 4; ++mi)
      #pragma unroll
      for (int ni = 0; ni < 4; ++ni)
        acc[mi][ni] = mfma16(am[mi], bm[ni], acc[mi][ni]);
  }

  #pragma unroll
  for (int mi = 0; mi < 4; ++mi)
    #pragma unroll
    for (int ni = 0; ni < 4; ++ni) {
      const int d = n0 + wn + ni * 16 + c16;
      const int ff = d >> 6, cc = d & 63;
      const int t = m0 + wm + mi * 16 + quad * 4;
      float4 o4;
      o4.x = acc[mi][ni][0]; o4.y = acc[mi][ni][1];
      o4.z = acc[mi][ni][2]; o4.w = acc[mi][ni][3];
      *(float4*)&out[(((size_t)b * 64 + cc) * 40 + ff) * 512 + t] = o4;
    }
}

// =====================================================================
extern "C" void kernel_launch(void* const* d_in, const int* in_sizes, int n_in,
                              void* d_out, int out_size, void* d_ws, size_t ws_size,
                              hipStream_t stream)
{
  const float* x  = (const float*)d_in[0];
  const float* Wq = (const float*)d_in[1];
  const float* Wk = (const float*)d_in[2];
  const float* Wv = (const float*)d_in[3];
  float* out = (float*)d_out;

  // workspace layout (bytes):
  //   Q  [16][512][2560] bf16 : 41,943,040
  //   K  [16][512][2560] bf16 : 41,943,040
  //   Vt [16][2560][512] bf16 : 41,943,040
  //   S  [16][512][512]  fp32 : 16,777,216
  //   A  [16][512][512]  bf16 :  8,388,608   (total 150,994,944)
  char* ws = (char*)d_ws;
  constexpr size_t QB = (size_t)B_ * T_ * D_ * 2;
  short* Q  = (short*)(ws);
  short* Kt = (short*)(ws + QB);
  short* Vt = (short*)(ws + 2 * QB);
  float* S  = (float*)(ws + 3 * QB);
  short* At = (short*)(ws + 3 * QB + (size_t)B_ * T_ * T_ * 4);

  proj_kernel<<<dim3(4, 40, 16), 256, 0, stream>>>(x, Wq, Wk, Wv, Q, Kt, Vt);
  scores_kernel<<<dim3(32, 16), 256, 0, stream>>>(Q, Kt, S);
  softmax_kernel<<<dim3(128, 16), 256, 0, stream>>>(S, At);
  pv_kernel<<<dim3(80, 16), 256, 0, stream>>>(At, Vt, out);
}

// Round 3
// 274.906 us; speedup vs baseline: 1.1639x; 1.1639x over previous
//
#include <hip/hip_runtime.h>

// ---------- problem dims ----------
constexpr int B_ = 16, C_ = 64, F_ = 40, T_ = 512;
constexpr int D_ = F_ * C_;              // 2560
constexpr float SCALE = 0.019764235376052372f;  // 1/sqrt(2560), baked into Wq

// ---------- types ----------
typedef __attribute__((ext_vector_type(8))) short s16x8;
typedef __attribute__((ext_vector_type(4))) short s16x4;
typedef __attribute__((ext_vector_type(4))) float f32x4;

static __device__ __forceinline__ short f2bf(float f) {
  union { float f; unsigned u; } v; v.f = f;
  unsigned r = v.u + 0x7fffu + ((v.u >> 16) & 1u);   // RNE, no NaN inputs
  return (short)(r >> 16);
}

static __device__ __forceinline__ f32x4 mfma16(s16x8 a, s16x8 b, f32x4 c) {
  return __builtin_amdgcn_mfma_f32_16x16x32_bf16(a, b, c, 0, 0, 0);
}

// async 16B global->LDS (wave-uniform LDS base + lane*16 placement)
static __device__ __forceinline__ void gl2lds16(const short* g, short* l) {
  __builtin_amdgcn_global_load_lds(
      (const __attribute__((address_space(1))) unsigned int*)g,
      (__attribute__((address_space(3))) unsigned int*)l, 16, 0, 0);
}

// =====================================================================
// Kernel 0: convert Wq,Wk,Wv fp32 -> bf16 once.  Wq pre-scaled by SCALE.
// Wb layout: [p][o][c], p in {q,k,v}, 64x64 each.
// =====================================================================
__global__ __launch_bounds__(256) void wcvt_kernel(
    const float* __restrict__ Wq, const float* __restrict__ Wk,
    const float* __restrict__ Wv, short* __restrict__ Wb)
{
  const int i = blockIdx.x * 256 + threadIdx.x;    // granule of 4 floats
  const float* src = (i < 1024) ? Wq : (i < 2048) ? Wk : Wv;
  const float sc = (i < 1024) ? SCALE : 1.0f;
  const float4 v = *(const float4*)(src + (i & 1023) * 4);
  s16x4 s;
  s[0] = f2bf(v.x * sc); s[1] = f2bf(v.y * sc);
  s[2] = f2bf(v.z * sc); s[3] = f2bf(v.w * sc);
  *(s16x4*)&Wb[i * 4] = s;
}

// =====================================================================
// Kernel 1: 1x1-conv projections.  Per block: one (b, f, 128-wide t tile).
// W fragments are bf16 16B loads from the hot 24KB Wb region (no converts).
// Q,K stored [b][t][d] bf16; V stored [b][d][t] via operand-swapped MFMA.
// =====================================================================
__global__ __launch_bounds__(256) void proj_kernel(
    const float* __restrict__ x, const short* __restrict__ Wb,
    short* __restrict__ Q, short* __restrict__ K, short* __restrict__ V)
{
  constexpr int XS = 132;   // X lds row stride (shorts) — 0 conflicts measured
  __shared__ __align__(16) short Xl[64 * XS];   // [c][t] tile, 16.9 KB

  const int b = blockIdx.z, f = blockIdx.y, tt = blockIdx.x;  // tt: 0..3
  const int tid = threadIdx.x;

  // stage X tile [64 c][128 t] as bf16 (coalesced float4 loads)
  const float* xp = x + (((size_t)b * 64) * 40 + f) * 512 + tt * 128;
  #pragma unroll
  for (int it = 0; it < 8; ++it) {          // 64c x 32 float4-granules
    const int i = tid + it * 256;
    const int c = i >> 5, j = i & 31;
    const float4 v4 = *(const float4*)(xp + (size_t)c * (F_ * T_) + j * 4);
    s16x4 s4; s4[0] = f2bf(v4.x); s4[1] = f2bf(v4.y);
    s4[2] = f2bf(v4.z); s4[3] = f2bf(v4.w);
    *(s16x4*)&Xl[c * XS + j * 4] = s4;
  }
  __syncthreads();

  const int w = tid >> 6, lane = tid & 63;
  const int quad = lane >> 4, c16 = lane & 15;
  const int tl = w * 32;                    // wave's t-base within tile

  // X fragments, shared by all three projections.
  s16x8 bfrag[2][2];
  #pragma unroll
  for (int ni = 0; ni < 2; ++ni)
    #pragma unroll
    for (int ks = 0; ks < 2; ++ks) {
      const int t = tl + ni * 16 + c16;
      const int cb = ks * 32 + quad * 8;
      s16x8 tmp;
      #pragma unroll
      for (int j = 0; j < 8; ++j) tmp[j] = Xl[(cb + j) * XS + t];
      bfrag[ni][ks] = tmp;
    }

  #pragma unroll
  for (int p = 0; p < 3; ++p) {
    const short* Wp = Wb + p * 4096;
    s16x8 wfrag[4][2];
    #pragma unroll
    for (int mi = 0; mi < 4; ++mi)
      #pragma unroll
      for (int ks = 0; ks < 2; ++ks)
        wfrag[mi][ks] = *(const s16x8*)(Wp + (mi * 16 + c16) * 64 + ks * 32 + quad * 8);

    if (p < 2) {
      // D[m=o][n=t]
      f32x4 acc[4][2] = {};
      #pragma unroll
      for (int ks = 0; ks < 2; ++ks)
        #pragma unroll
        for (int mi = 0; mi < 4; ++mi)
          #pragma unroll
          for (int ni = 0; ni < 2; ++ni)
            acc[mi][ni] = mfma16(wfrag[mi][ks], bfrag[ni][ks], acc[mi][ni]);
      short* outp = (p == 0) ? Q : K;
      #pragma unroll
      for (int mi = 0; mi < 4; ++mi)
        #pragma unroll
        for (int ni = 0; ni < 2; ++ni) {
          const int t = tt * 128 + tl + ni * 16 + c16;
          const int o = mi * 16 + quad * 4;
          s16x4 s4;
          #pragma unroll
          for (int r = 0; r < 4; ++r) s4[r] = f2bf(acc[mi][ni][r]);
          *(s16x4*)&outp[((size_t)(b * 512 + t)) * D_ + f * 64 + o] = s4;
        }
    } else {
      // swapped: D[m=t][n=o] -> regs are 4 consecutive t
      f32x4 acc[2][4] = {};
      #pragma unroll
      for (int ks = 0; ks < 2; ++ks)
        #pragma unroll
        for (int ni = 0; ni < 2; ++ni)
          #pragma unroll
          for (int mi = 0; mi < 4; ++mi)
            acc[ni][mi] = mfma16(bfrag[ni][ks], wfrag[mi][ks], acc[ni][mi]);
      #pragma unroll
      for (int ni = 0; ni < 2; ++ni)
        #pragma unroll
        for (int mi = 0; mi < 4; ++mi) {
          const int t = tt * 128 + tl + ni * 16 + quad * 4;
          const int o = mi * 16 + c16;
          s16x4 s4;
          #pragma unroll
          for (int r = 0; r < 4; ++r) s4[r] = f2bf(acc[ni][mi][r]);
          *(s16x4*)&V[((size_t)(b * D_ + f * 64 + o)) * 512 + t] = s4;
        }
    }
  }
}

// =====================================================================
// Kernel 2: S = Qs K^T  (scale baked into Qs).  64x128 tile, BK=64,
// global_load_lds staging with XOR-swizzled placement (conflict-free
// ds_read_b128, loop-invariant read addresses).
// =====================================================================
__global__ __launch_bounds__(256) void scores_kernel(
    const short* __restrict__ Q, const short* __restrict__ K,
    float* __restrict__ S)
{
  __shared__ __align__(16) short As[64 * 64];    // 8 KB
  __shared__ __align__(16) short Bs[128 * 64];   // 16 KB
  const int b = blockIdx.y;
  const int mt = blockIdx.x >> 2, nt = blockIdx.x & 3;
  const int m0 = mt * 64, n0 = nt * 128;
  const int tid = threadIdx.x;
  const int w = tid >> 6, lane = tid & 63, quad = lane >> 4, c16 = lane & 15;
  const int wm = (w >> 1) * 32, wn = (w & 1) * 64;

  const short* qb = Q + (size_t)(b * 512 + m0) * D_;
  const short* kb = K + (size_t)(b * 512 + n0) * D_;

  // staging: thread covers LDS granule s = i*256+tid; fetches the global
  // granule that belongs at swizzled slot:  data gcol = (s&7) ^ (row&7)
  const short* agp[2];
  short* aldsb[2];
  #pragma unroll
  for (int i = 0; i < 2; ++i) {
    const int s = i * 256 + tid, row = s >> 3;
    const int g = (s & 7) ^ (row & 7);
    agp[i] = qb + (size_t)row * D_ + g * 8;
    aldsb[i] = &As[(i * 256 + w * 64) * 8];
  }
  const short* bgp[4];
  short* bldsb[4];
  #pragma unroll
  for (int i = 0; i < 4; ++i) {
    const int s = i * 256 + tid, row = s >> 3;
    const int g = (s & 7) ^ (row & 7);
    bgp[i] = kb + (size_t)row * D_ + g * 8;
    bldsb[i] = &Bs[(i * 256 + w * 64) * 8];
  }

  // loop-invariant swizzled fragment addresses
  const short* amp[2][2];
  #pragma unroll
  for (int mi = 0; mi < 2; ++mi)
    #pragma unroll
    for (int ks = 0; ks < 2; ++ks) {
      const int row = wm + mi * 16 + c16;
      const int g = (ks * 4 + quad) ^ (row & 7);
      amp[mi][ks] = &As[row * 64 + g * 8];
    }
  const short* bmp[4][2];
  #pragma unroll
  for (int ni = 0; ni < 4; ++ni)
    #pragma unroll
    for (int ks = 0; ks < 2; ++ks) {
      const int row = wn + ni * 16 + c16;
      const int g = (ks * 4 + quad) ^ (row & 7);
      bmp[ni][ks] = &Bs[row * 64 + g * 8];
    }

  f32x4 acc[2][4] = {};
  constexpr int NK = D_ / 64;   // 40
  for (int kk = 0; kk < NK; ++kk) {
    const int ko = kk * 64;
    __syncthreads();
    #pragma unroll
    for (int i = 0; i < 2; ++i) gl2lds16(agp[i] + ko, aldsb[i]);
    #pragma unroll
    for (int i = 0; i < 4; ++i) gl2lds16(bgp[i] + ko, bldsb[i]);
    __syncthreads();
    s16x8 am[2][2], bm[4][2];
    #pragma unroll
    for (int mi = 0; mi < 2; ++mi)
      #pragma unroll
      for (int ks = 0; ks < 2; ++ks) am[mi][ks] = *(const s16x8*)amp[mi][ks];
    #pragma unroll
    for (int ni = 0; ni < 4; ++ni)
      #pragma unroll
      for (int ks = 0; ks < 2; ++ks) bm[ni][ks] = *(const s16x8*)bmp[ni][ks];
    #pragma unroll
    for (int ks = 0; ks < 2; ++ks)
      #pragma unroll
      for (int mi = 0; mi < 2; ++mi)
        #pragma unroll
        for (int ni = 0; ni < 4; ++ni)
          acc[mi][ni] = mfma16(am[mi][ks], bm[ni][ks], acc[mi][ni]);
  }

  float* sp = S + (size_t)b * 512 * 512;
  #pragma unroll
  for (int mi = 0; mi < 2; ++mi)
    #pragma unroll
    for (int ni = 0; ni < 4; ++ni) {
      const int kcol = n0 + wn + ni * 16 + c16;
      const int qr = m0 + wm + mi * 16 + quad * 4;
      #pragma unroll
      for (int r = 0; r < 4; ++r)
        sp[(size_t)(qr + r) * 512 + kcol] = acc[mi][ni][r];
    }
}

// =====================================================================
// Kernel 3: row softmax, S fp32 -> A bf16.  One WAVE per (b,q) row.
// =====================================================================
__global__ __launch_bounds__(256) void softmax_kernel(
    const float* __restrict__ S, short* __restrict__ A)
{
  const int b = blockIdx.y;
  const int tid = threadIdx.x, w = tid >> 6, lane = tid & 63;
  const int q = blockIdx.x * 4 + w;
  const float* row = S + ((size_t)b * 512 + q) * 512;

  const float4 v0 = *(const float4*)(row + lane * 4);
  const float4 v1 = *(const float4*)(row + 256 + lane * 4);
  float e[8] = {v0.x, v0.y, v0.z, v0.w, v1.x, v1.y, v1.z, v1.w};

  float m = e[0];
  #pragma unroll
  for (int i = 1; i < 8; ++i) m = fmaxf(m, e[i]);
  #pragma unroll
  for (int off = 1; off < 64; off <<= 1) m = fmaxf(m, __shfl_xor(m, off));

  float s = 0.f;
  #pragma unroll
  for (int i = 0; i < 8; ++i) { e[i] = __expf(e[i] - m); s += e[i]; }
  #pragma unroll
  for (int off = 1; off < 64; off <<= 1) s += __shfl_xor(s, off);

  const float inv = 1.0f / s;
  short* arow = A + ((size_t)b * 512 + q) * 512;
  s16x4 o0, o1;
  #pragma unroll
  for (int i = 0; i < 4; ++i) { o0[i] = f2bf(e[i] * inv); o1[i] = f2bf(e[i + 4] * inv); }
  *(s16x4*)&arow[lane * 4] = o0;
  *(s16x4*)&arow[256 + lane * 4] = o1;
}

// =====================================================================
// Kernel 4: out = A @ V.  128x128 tile, BK=64, global_load_lds + swizzle.
// Epilogue writes fp32 directly in [b][c][f][t] via float4.
// =====================================================================
__global__ __launch_bounds__(256) void pv_kernel(
    const short* __restrict__ A, const short* __restrict__ V,
    float* __restrict__ out)
{
  __shared__ __align__(16) short As[128 * 64];   // 16 KB
  __shared__ __align__(16) short Bs[128 * 64];   // 16 KB
  const int b = blockIdx.y;
  const int mt = blockIdx.x / 20, dt = blockIdx.x % 20;
  const int m0 = mt * 128, n0 = dt * 128;
  const int tid = threadIdx.x;
  const int w = tid >> 6, lane = tid & 63, quad = lane >> 4, c16 = lane & 15;
  const int wm = (w >> 1) * 64, wn = (w & 1) * 64;

  const short* ab = A + ((size_t)b * 512 + m0) * 512;
  const short* vb = V + ((size_t)b * D_ + n0) * 512;

  const short* agp[4]; short* aldsb[4];
  const short* bgp[4]; short* bldsb[4];
  #pragma unroll
  for (int i = 0; i < 4; ++i) {
    const int s = i * 256 + tid, row = s >> 3;
    const int g = (s & 7) ^ (row & 7);
    agp[i] = ab + (size_t)row * 512 + g * 8;
    bgp[i] = vb + (size_t)row * 512 + g * 8;
    aldsb[i] = &As[(i * 256 + w * 64) * 8];
    bldsb[i] = &Bs[(i * 256 + w * 64) * 8];
  }

  const short* amp[4][2];
  const short* bmp[4][2];
  #pragma unroll
  for (int mi = 0; mi < 4; ++mi)
    #pragma unroll
    for (int ks = 0; ks < 2; ++ks) {
      const int rowa = wm + mi * 16 + c16;
      const int rowb = wn + mi * 16 + c16;
      amp[mi][ks] = &As[rowa * 64 + (((ks * 4 + quad) ^ (rowa & 7)) * 8)];
      bmp[mi][ks] = &Bs[rowb * 64 + (((ks * 4 + quad) ^ (rowb & 7)) * 8)];
    }

  f32x4 acc[4][4] = {};
  constexpr int NK = 512 / 64;   // 8
  for (int kk = 0; kk < NK; ++kk) {
    const int ko = kk * 64;
    __syncthreads();
    #pragma unroll
    for (int i = 0; i < 4; ++i) gl2lds16(agp[i] + ko, aldsb[i]);
    #pragma unroll
    for (int i = 0; i < 4; ++i) gl2lds16(bgp[i] + ko, bldsb[i]);
    __syncthreads();
    s16x8 am[4][2], bm[4][2];
    #pragma unroll
    for (int mi = 0; mi < 4; ++mi)
      #pragma unroll
      for (int ks = 0; ks < 2; ++ks) {
        am[mi][ks] = *(const s16x8*)amp[mi][ks];
        bm[mi][ks] = *(const s16x8*)bmp[mi][ks];
      }
    #pragma unroll
    for (int ks = 0; ks < 2; ++ks)
      #pragma unroll
      for (int mi = 0; mi < 4; ++mi)
        #pragma unroll
        for (int ni = 0; ni < 4; ++ni)
          acc[mi][ni] = mfma16(am[mi][ks], bm[ni][ks], acc[mi][ni]);
  }

  #pragma unroll
  for (int mi = 0; mi < 4; ++mi)
    #pragma unroll
    for (int ni = 0; ni < 4; ++ni) {
      const int d = n0 + wn + ni * 16 + c16;
      const int ff = d >> 6, cc = d & 63;
      const int t = m0 + wm + mi * 16 + quad * 4;
      float4 o4;
      o4.x = acc[mi][ni][0]; o4.y = acc[mi][ni][1];
      o4.z = acc[mi][ni][2]; o4.w = acc[mi][ni][3];
      *(float4*)&out[(((size_t)b * 64 + cc) * 40 + ff) * 512 + t] = o4;
    }
}

// =====================================================================
extern "C" void kernel_launch(void* const* d_in, const int* in_sizes, int n_in,
                              void* d_out, int out_size, void* d_ws, size_t ws_size,
                              hipStream_t stream)
{
  const float* x  = (const float*)d_in[0];
  const float* Wq = (const float*)d_in[1];
  const float* Wk = (const float*)d_in[2];
  const float* Wv = (const float*)d_in[3];
  float* out = (float*)d_out;

  // workspace layout (bytes):
  //   Q  [16][512][2560] bf16 : 41,943,040
  //   K  [16][512][2560] bf16 : 41,943,040
  //   Vt [16][2560][512] bf16 : 41,943,040
  //   S  [16][512][512]  fp32 : 16,777,216   (Wb bf16 24KB overlaps S head:
  //   A  [16][512][512]  bf16 :  8,388,608    Wb dead before scores writes S)
  char* ws = (char*)d_ws;
  constexpr size_t QB = (size_t)B_ * T_ * D_ * 2;
  short* Q  = (short*)(ws);
  short* Kt = (short*)(ws + QB);
  short* Vt = (short*)(ws + 2 * QB);
  float* S  = (float*)(ws + 3 * QB);
  short* Wb = (short*)(ws + 3 * QB);   // overlaps S (sequential lifetime)
  short* At = (short*)(ws + 3 * QB + (size_t)B_ * T_ * T_ * 4);

  wcvt_kernel<<<dim3(12), 256, 0, stream>>>(Wq, Wk, Wv, Wb);
  proj_kernel<<<dim3(4, 40, 16), 256, 0, stream>>>(x, Wb, Q, Kt, Vt);
  scores_kernel<<<dim3(32, 16), 256, 0, stream>>>(Q, Kt, S);
  softmax_kernel<<<dim3(128, 16), 256, 0, stream>>>(S, At);
  pv_kernel<<<dim3(80, 16), 256, 0, stream>>>(At, Vt, out);
}